// Round 1
// baseline (325.708 us; speedup 1.0000x reference)
//
#include <hip/hip_runtime.h>

// CARAFE: N=4, H=W=64, INC=256, CM=64, KUP=5 (k2=25), DELTA=2 (d2=4),
// KENC=3, enc_out=100, OUTC=256, H2=W2=128. All fp32.

namespace {
constexpr int kN = 4, kH = 64, kW = 64, kINC = 256, kCM = 64;
constexpr int kENC = 100, kH2 = 128, kW2 = 128, kOUTC = 256;
constexpr int kHW = kH * kW;       // 4096
constexpr int kHW2 = kH2 * kW2;    // 16384
}

// ---------- kernel 1: 1x1 down conv: x(N,256,64,64) -> down(N,64,64,64) ----------
// block = 256 threads = 4 h-rows x 64 w. Each thread computes 4 cm outputs
// (x value loaded once, 4 FMAs) to cut L2 traffic 4x.
__global__ __launch_bounds__(256) void k_down(
    const float* __restrict__ x, const float* __restrict__ wd,
    const float* __restrict__ bd, float* __restrict__ down) {
  const int b = blockIdx.x;                 // 1024 blocks: hg(16) x cmg(16) x n(4)
  const int hg = b & 15, cmg = (b >> 4) & 15, n = b >> 8;
  const int tid = threadIdx.x;
  const int h = (hg << 2) + (tid >> 6), w = tid & 63;
  const int c0 = cmg << 2;
  const float* xb = x + (size_t)n * kINC * kHW + h * kW + w;
  const float* w0 = wd + (size_t)(c0    ) * kINC;
  const float* w1 = wd + (size_t)(c0 + 1) * kINC;
  const float* w2 = wd + (size_t)(c0 + 2) * kINC;
  const float* w3 = wd + (size_t)(c0 + 3) * kINC;
  float a0 = bd[c0], a1 = bd[c0 + 1], a2 = bd[c0 + 2], a3 = bd[c0 + 3];
#pragma unroll 8
  for (int c = 0; c < kINC; ++c) {
    const float xv = xb[(size_t)c * kHW];
    a0 += w0[c] * xv; a1 += w1[c] * xv; a2 += w2[c] * xv; a3 += w3[c] * xv;
  }
  float* ob = down + ((size_t)(n * kCM + c0) * kHW) + h * kW + w;
  ob[0] = a0; ob[kHW] = a1; ob[2 * kHW] = a2; ob[3 * kHW] = a3;
}

// ---------- kernel 2: 3x3 enc conv: down(N,64,64,64) -> enc(N,100,64,64) ----------
// Each thread computes 4 output channels at one (h,w); taps outer (wave-uniform
// row validity), ci inner. Weight reads are wave-uniform -> scalar loads.
__global__ __launch_bounds__(256) void k_enc(
    const float* __restrict__ down, const float* __restrict__ we,
    const float* __restrict__ be, float* __restrict__ enc) {
  const int b = blockIdx.x;                 // 1600 blocks: hg(16) x (og(25) x n(4))
  const int hg = b & 15;
  const int t = b >> 4;
  const int og = t % 25, n = t / 25;
  const int tid = threadIdx.x;
  const int h = (hg << 2) + (tid >> 6), w = tid & 63;
  const int o0 = og << 2;
  const float* db = down + (size_t)n * kCM * kHW;
  float acc[4] = {be[o0], be[o0 + 1], be[o0 + 2], be[o0 + 3]};
#pragma unroll
  for (int kh = 0; kh < 3; ++kh) {
    const int hh = h + kh - 1;
    if (hh < 0 || hh >= kH) continue;       // wave-uniform branch (h uniform per wave)
#pragma unroll
    for (int kw = 0; kw < 3; ++kw) {
      const int ww = w + kw - 1;
      if (ww < 0 || ww >= kW) continue;     // diverges only at w=0/63 lanes
      const int tap = kh * 3 + kw;
      const float* dptr = db + hh * kW + ww;
#pragma unroll 8
      for (int ci = 0; ci < kCM; ++ci) {
        const float v = dptr[(size_t)ci * kHW];
        acc[0] += we[(size_t)(o0    ) * 576 + ci * 9 + tap] * v;
        acc[1] += we[(size_t)(o0 + 1) * 576 + ci * 9 + tap] * v;
        acc[2] += we[(size_t)(o0 + 2) * 576 + ci * 9 + tap] * v;
        acc[3] += we[(size_t)(o0 + 3) * 576 + ci * 9 + tap] * v;
      }
    }
  }
  float* ob = enc + ((size_t)(n * kENC + o0) * kHW) + h * kW + w;
  ob[0] = acc[0]; ob[kHW] = acc[1]; ob[2 * kHW] = acc[2]; ob[3 * kHW] = acc[3];
}

// ---------- kernel 3: softmax over the 25 kernel taps, in place ----------
// channel = k*4 + d; softmax over k for each (n, d, h, w). In-place is safe:
// each thread owns disjoint channels and reads all before writing.
__global__ __launch_bounds__(256) void k_softmax(float* __restrict__ buf) {
  const int b = blockIdx.x;                 // 256 blocks: hg(16) x d(4) x n(4)
  const int hg = b & 15, d = (b >> 4) & 3, n = b >> 6;
  const int tid = threadIdx.x;
  const int h = (hg << 2) + (tid >> 6), w = tid & 63;
  float* base = buf + ((size_t)n * kENC + d) * kHW + h * kW + w;
  float v[25];
  float m = -1e30f;
#pragma unroll
  for (int k = 0; k < 25; ++k) { v[k] = base[(size_t)k * 4 * kHW]; m = fmaxf(m, v[k]); }
  float s = 0.f;
#pragma unroll
  for (int k = 0; k < 25; ++k) { v[k] = __expf(v[k] - m); s += v[k]; }
  const float inv = 1.f / s;
#pragma unroll
  for (int k = 0; k < 25; ++k) base[(size_t)k * 4 * kHW] = v[k] * inv;
}

// ---------- kernel 4: reassembly + pixel shuffle: -> up(N,256,128,128) ----------
// Thread handles 4 input channels x all 4 subpixels at one (h,w): 25 taps,
// per tap 4 kern loads + 4 x loads + 16 FMA. Writes float2 pairs (coalesced).
__global__ __launch_bounds__(256) void k_reassemble(
    const float* __restrict__ x, const float* __restrict__ kern,
    float* __restrict__ up) {
  const int b = blockIdx.x;                 // 4096 blocks: hg(16) x cg(64) x n(4)
  const int hg = b & 15, cg = (b >> 4) & 63, n = b >> 10;
  const int tid = threadIdx.x;
  const int h = (hg << 2) + (tid >> 6), w = tid & 63;
  const int c0 = cg << 2;
  const float* kb = kern + (size_t)n * kENC * kHW + h * kW + w;
  const float* xb = x + (size_t)(n * kINC + c0) * kHW;
  float acc[4][4] = {};                     // [c][d]
#pragma unroll
  for (int kh = 0; kh < 5; ++kh) {
    const int hh = h + kh - 2;
    if (hh < 0 || hh >= kH) continue;       // wave-uniform
#pragma unroll
    for (int kw = 0; kw < 5; ++kw) {
      const int ww = w + kw - 2;
      if (ww < 0 || ww >= kW) continue;
      const int k = kh * 5 + kw;
      const float kv0 = kb[(size_t)(k * 4    ) * kHW];
      const float kv1 = kb[(size_t)(k * 4 + 1) * kHW];
      const float kv2 = kb[(size_t)(k * 4 + 2) * kHW];
      const float kv3 = kb[(size_t)(k * 4 + 3) * kHW];
      const int xoff = hh * kW + ww;
#pragma unroll
      for (int u = 0; u < 4; ++u) {
        const float xv = xb[(size_t)u * kHW + xoff];
        acc[u][0] += xv * kv0; acc[u][1] += xv * kv1;
        acc[u][2] += xv * kv2; acc[u][3] += xv * kv3;
      }
    }
  }
  // pixel shuffle: d = i*2+j -> (y,x) = (2h+i, 2w+j); (2w,2w+1) pair -> float2
#pragma unroll
  for (int u = 0; u < 4; ++u) {
#pragma unroll
    for (int i = 0; i < 2; ++i) {
      float* dst = up + ((size_t)(n * kINC + c0 + u) * kH2 + (2 * h + i)) * kW2 + 2 * w;
      *(float2*)dst = make_float2(acc[u][i * 2], acc[u][i * 2 + 1]);
    }
  }
}

// ---------- kernel 5: 1x1 out conv as GEMM: out[o][p] = sum_c W[o][c] up[c][p] ----------
// Per n: M=256 (o) x N=16384 (p) x K=256. 64x64 tile, 4x4 microtile, BK=16.
__global__ __launch_bounds__(256) void k_outconv(
    const float* __restrict__ up, const float* __restrict__ wo,
    const float* __restrict__ bo, float* __restrict__ out) {
  const int b = blockIdx.x;                 // 4096 blocks: pT(256) x oT(4) x n(4)
  const int pT = b & 255, oT = (b >> 8) & 3, n = b >> 10;
  const int p0 = pT << 6, o0 = oT << 6;
  const int tid = threadIdx.x;
  const int tx = tid & 15, ty = tid >> 4;
  __shared__ float As[16][64];              // [k][o] (A stored transposed)
  __shared__ float Bs[16][64];              // [k][p]
  const float* Ab = wo + (size_t)o0 * kINC;
  const float* Bb = up + (size_t)n * kINC * kHW2 + p0;
  float acc[4][4] = {};
  const int ar = tid >> 2, ac = (tid & 3) << 2;   // A: 64 rows x 16 k, float4 per thread
  const int br = tid >> 4, bc = (tid & 15) << 2;  // B: 16 rows x 64 p, float4 per thread
  for (int k0 = 0; k0 < kINC; k0 += 16) {
    const float4 av = *(const float4*)(Ab + (size_t)ar * kINC + k0 + ac);
    As[ac + 0][ar] = av.x; As[ac + 1][ar] = av.y;
    As[ac + 2][ar] = av.z; As[ac + 3][ar] = av.w;
    const float4 bv = *(const float4*)(Bb + (size_t)(k0 + br) * kHW2 + bc);
    *(float4*)(&Bs[br][bc]) = bv;
    __syncthreads();
#pragma unroll
    for (int kk = 0; kk < 16; ++kk) {
      const float a0 = As[kk][ty * 4 + 0], a1 = As[kk][ty * 4 + 1];
      const float a2 = As[kk][ty * 4 + 2], a3 = As[kk][ty * 4 + 3];
      const float b0 = Bs[kk][tx * 4 + 0], b1 = Bs[kk][tx * 4 + 1];
      const float b2 = Bs[kk][tx * 4 + 2], b3 = Bs[kk][tx * 4 + 3];
      acc[0][0] += a0 * b0; acc[0][1] += a0 * b1; acc[0][2] += a0 * b2; acc[0][3] += a0 * b3;
      acc[1][0] += a1 * b0; acc[1][1] += a1 * b1; acc[1][2] += a1 * b2; acc[1][3] += a1 * b3;
      acc[2][0] += a2 * b0; acc[2][1] += a2 * b1; acc[2][2] += a2 * b2; acc[2][3] += a2 * b3;
      acc[3][0] += a3 * b0; acc[3][1] += a3 * b1; acc[3][2] += a3 * b2; acc[3][3] += a3 * b3;
    }
    __syncthreads();
  }
#pragma unroll
  for (int i = 0; i < 4; ++i) {
    const int o = o0 + ty * 4 + i;
    const float bias = bo[o];
    float4 r = make_float4(acc[i][0] + bias, acc[i][1] + bias,
                           acc[i][2] + bias, acc[i][3] + bias);
    *(float4*)(out + ((size_t)(n * kOUTC + o) * kHW2) + p0 + tx * 4) = r;
  }
}

extern "C" void kernel_launch(void* const* d_in, const int* in_sizes, int n_in,
                              void* d_out, int out_size, void* d_ws, size_t ws_size,
                              hipStream_t stream) {
  const float* x  = (const float*)d_in[0];   // (4,256,64,64)
  const float* wd = (const float*)d_in[1];   // (64,256,1,1)
  const float* bd = (const float*)d_in[2];   // (64,)
  const float* we = (const float*)d_in[3];   // (100,64,3,3)
  const float* be = (const float*)d_in[4];   // (100,)
  const float* wo = (const float*)d_in[5];   // (256,256,1,1)
  const float* bo = (const float*)d_in[6];   // (256,)
  float* out = (float*)d_out;                // (4,256,128,128)

  // workspace layout (floats): down | enc(kern, softmaxed in place) | up
  float* down = (float*)d_ws;                // 4*64*4096      = 1,048,576
  float* enc  = down + 1048576;              // 4*100*4096     = 1,638,400
  float* up   = enc + 1638400;               // 4*256*16384    = 16,777,216 (16B-aligned)

  k_down<<<1024, 256, 0, stream>>>(x, wd, bd, down);
  k_enc<<<1600, 256, 0, stream>>>(down, we, be, enc);
  k_softmax<<<256, 256, 0, stream>>>(enc);
  k_reassemble<<<4096, 256, 0, stream>>>(x, enc, up);
  k_outconv<<<4096, 256, 0, stream>>>(up, wo, bo, out);
}

// Round 2
// 249.469 us; speedup vs baseline: 1.3056x; 1.3056x over previous
//
#include <hip/hip_runtime.h>

// CARAFE restructured: out = W_out applied at LOW res (z = Wo*x), then fused
// reassembly+pixel_shuffle+bias writes d_out directly.
// N=4, H=W=64, INC=256, CM=64, KUP=5, DELTA=2, enc_out=100, OUTC=256.

namespace {
constexpr int kN = 4, kH = 64, kW = 64, kINC = 256, kCM = 64;
constexpr int kENC = 100, kH2 = 128, kW2 = 128, kOUTC = 256;
constexpr int kHW = kH * kW;       // 4096
constexpr int kHW2 = kH2 * kW2;    // 16384
}

// ---------- kernel 1: 1x1 down conv: x(N,256,64,64) -> down(N,64,64,64) ----------
__global__ __launch_bounds__(256) void k_down(
    const float* __restrict__ x, const float* __restrict__ wd,
    const float* __restrict__ bd, float* __restrict__ down) {
  const int b = blockIdx.x;                 // 1024 blocks: hg(16) x cmg(16) x n(4)
  const int hg = b & 15, cmg = (b >> 4) & 15, n = b >> 8;
  const int tid = threadIdx.x;
  const int h = (hg << 2) + (tid >> 6), w = tid & 63;
  const int c0 = cmg << 2;
  const float* xb = x + (size_t)n * kINC * kHW + h * kW + w;
  const float* w0 = wd + (size_t)(c0    ) * kINC;
  const float* w1 = wd + (size_t)(c0 + 1) * kINC;
  const float* w2 = wd + (size_t)(c0 + 2) * kINC;
  const float* w3 = wd + (size_t)(c0 + 3) * kINC;
  float a0 = bd[c0], a1 = bd[c0 + 1], a2 = bd[c0 + 2], a3 = bd[c0 + 3];
#pragma unroll 8
  for (int c = 0; c < kINC; ++c) {
    const float xv = xb[(size_t)c * kHW];
    a0 += w0[c] * xv; a1 += w1[c] * xv; a2 += w2[c] * xv; a3 += w3[c] * xv;
  }
  float* ob = down + ((size_t)(n * kCM + c0) * kHW) + h * kW + w;
  ob[0] = a0; ob[kHW] = a1; ob[2 * kHW] = a2; ob[3 * kHW] = a3;
}

// ---------- kernel 2: 3x3 enc conv: down(N,64,64,64) -> enc(N,100,64,64) ----------
__global__ __launch_bounds__(256) void k_enc(
    const float* __restrict__ down, const float* __restrict__ we,
    const float* __restrict__ be, float* __restrict__ enc) {
  const int b = blockIdx.x;                 // 1600 blocks: hg(16) x (og(25) x n(4))
  const int hg = b & 15;
  const int t = b >> 4;
  const int og = t % 25, n = t / 25;
  const int tid = threadIdx.x;
  const int h = (hg << 2) + (tid >> 6), w = tid & 63;
  const int o0 = og << 2;
  const float* db = down + (size_t)n * kCM * kHW;
  float acc[4] = {be[o0], be[o0 + 1], be[o0 + 2], be[o0 + 3]};
#pragma unroll
  for (int kh = 0; kh < 3; ++kh) {
    const int hh = h + kh - 1;
    if (hh < 0 || hh >= kH) continue;       // wave-uniform (h uniform per wave)
#pragma unroll
    for (int kw = 0; kw < 3; ++kw) {
      const int ww = w + kw - 1;
      if (ww < 0 || ww >= kW) continue;
      const int tap = kh * 3 + kw;
      const float* dptr = db + hh * kW + ww;
#pragma unroll 8
      for (int ci = 0; ci < kCM; ++ci) {
        const float v = dptr[(size_t)ci * kHW];
        acc[0] += we[(size_t)(o0    ) * 576 + ci * 9 + tap] * v;
        acc[1] += we[(size_t)(o0 + 1) * 576 + ci * 9 + tap] * v;
        acc[2] += we[(size_t)(o0 + 2) * 576 + ci * 9 + tap] * v;
        acc[3] += we[(size_t)(o0 + 3) * 576 + ci * 9 + tap] * v;
      }
    }
  }
  float* ob = enc + ((size_t)(n * kENC + o0) * kHW) + h * kW + w;
  ob[0] = acc[0]; ob[kHW] = acc[1]; ob[2 * kHW] = acc[2]; ob[3 * kHW] = acc[3];
}

// ---------- kernel 3: softmax over the 25 kernel taps, in place ----------
__global__ __launch_bounds__(256) void k_softmax(float* __restrict__ buf) {
  const int b = blockIdx.x;                 // 256 blocks: hg(16) x d(4) x n(4)
  const int hg = b & 15, d = (b >> 4) & 3, n = b >> 6;
  const int tid = threadIdx.x;
  const int h = (hg << 2) + (tid >> 6), w = tid & 63;
  float* base = buf + ((size_t)n * kENC + d) * kHW + h * kW + w;
  float v[25];
  float m = -1e30f;
#pragma unroll
  for (int k = 0; k < 25; ++k) { v[k] = base[(size_t)k * 4 * kHW]; m = fmaxf(m, v[k]); }
  float s = 0.f;
#pragma unroll
  for (int k = 0; k < 25; ++k) { v[k] = __expf(v[k] - m); s += v[k]; }
  const float inv = 1.f / s;
#pragma unroll
  for (int k = 0; k < 25; ++k) base[(size_t)k * 4 * kHW] = v[k] * inv;
}

// ---------- kernel 4: z = Wo * x (1x1, 256->256 at 64x64 res), no bias ----------
// Per n: M=256 (o) x N=4096 (p) x K=256. 64x64 tile, 4x4 microtile, BK=16.
__global__ __launch_bounds__(256) void k_zgemm(
    const float* __restrict__ x, const float* __restrict__ wo,
    float* __restrict__ z) {
  const int b = blockIdx.x;                 // 1024 blocks: pT(64) x oT(4) x n(4)
  const int pT = b & 63, oT = (b >> 6) & 3, n = b >> 8;
  const int p0 = pT << 6, o0 = oT << 6;
  const int tid = threadIdx.x;
  const int tx = tid & 15, ty = tid >> 4;
  __shared__ float As[16][64];              // [k][o]
  __shared__ float Bs[16][64];              // [k][p]
  const float* Ab = wo + (size_t)o0 * kINC;
  const float* Bb = x + (size_t)n * kINC * kHW + p0;
  float acc[4][4] = {};
  const int ar = tid >> 2, ac = (tid & 3) << 2;   // A: 64 rows x 16 k
  const int br = tid >> 4, bc = (tid & 15) << 2;  // B: 16 rows x 64 p
  for (int k0 = 0; k0 < kINC; k0 += 16) {
    const float4 av = *(const float4*)(Ab + (size_t)ar * kINC + k0 + ac);
    As[ac + 0][ar] = av.x; As[ac + 1][ar] = av.y;
    As[ac + 2][ar] = av.z; As[ac + 3][ar] = av.w;
    const float4 bv = *(const float4*)(Bb + (size_t)(k0 + br) * kHW + bc);
    *(float4*)(&Bs[br][bc]) = bv;
    __syncthreads();
#pragma unroll
    for (int kk = 0; kk < 16; ++kk) {
      const float a0 = As[kk][ty * 4 + 0], a1 = As[kk][ty * 4 + 1];
      const float a2 = As[kk][ty * 4 + 2], a3 = As[kk][ty * 4 + 3];
      const float b0 = Bs[kk][tx * 4 + 0], b1 = Bs[kk][tx * 4 + 1];
      const float b2 = Bs[kk][tx * 4 + 2], b3 = Bs[kk][tx * 4 + 3];
      acc[0][0] += a0 * b0; acc[0][1] += a0 * b1; acc[0][2] += a0 * b2; acc[0][3] += a0 * b3;
      acc[1][0] += a1 * b0; acc[1][1] += a1 * b1; acc[1][2] += a1 * b2; acc[1][3] += a1 * b3;
      acc[2][0] += a2 * b0; acc[2][1] += a2 * b1; acc[2][2] += a2 * b2; acc[2][3] += a2 * b3;
      acc[3][0] += a3 * b0; acc[3][1] += a3 * b1; acc[3][2] += a3 * b2; acc[3][3] += a3 * b3;
    }
    __syncthreads();
  }
#pragma unroll
  for (int i = 0; i < 4; ++i) {
    const int o = o0 + ty * 4 + i;
    *(float4*)(z + ((size_t)(n * kOUTC + o) * kHW) + p0 + tx * 4) =
        make_float4(acc[i][0], acc[i][1], acc[i][2], acc[i][3]);
  }
}

// ---------- kernel 5: fused reassembly + pixel shuffle + bias -> out ----------
// out[n,o,2h+i,2w+j] = bo[o] + sum_k kern[k*4+(i*2+j)](h,w) * z[n,o](h+kh-2,w+kw-2)
__global__ __launch_bounds__(256) void k_fused_out(
    const float* __restrict__ z, const float* __restrict__ kern,
    const float* __restrict__ bo, float* __restrict__ out) {
  const int b = blockIdx.x;                 // 4096 blocks: hg(16) x og(64) x n(4)
  const int hg = b & 15, og = (b >> 4) & 63, n = b >> 10;
  const int tid = threadIdx.x;
  const int h = (hg << 2) + (tid >> 6), w = tid & 63;
  const int o0 = og << 2;
  const float* kb = kern + (size_t)n * kENC * kHW + h * kW + w;
  const float* zb = z + (size_t)(n * kOUTC + o0) * kHW;
  float acc[4][4] = {};                     // [o][d]
#pragma unroll
  for (int kh = 0; kh < 5; ++kh) {
    const int hh = h + kh - 2;
    if (hh < 0 || hh >= kH) continue;       // wave-uniform
#pragma unroll
    for (int kw = 0; kw < 5; ++kw) {
      const int ww = w + kw - 2;
      if (ww < 0 || ww >= kW) continue;
      const int k = kh * 5 + kw;
      const float kv0 = kb[(size_t)(k * 4    ) * kHW];
      const float kv1 = kb[(size_t)(k * 4 + 1) * kHW];
      const float kv2 = kb[(size_t)(k * 4 + 2) * kHW];
      const float kv3 = kb[(size_t)(k * 4 + 3) * kHW];
      const int xoff = hh * kW + ww;
#pragma unroll
      for (int u = 0; u < 4; ++u) {
        const float zv = zb[(size_t)u * kHW + xoff];
        acc[u][0] += zv * kv0; acc[u][1] += zv * kv1;
        acc[u][2] += zv * kv2; acc[u][3] += zv * kv3;
      }
    }
  }
  // pixel shuffle: d = i*2+j -> (2h+i, 2w+j); write float2 pairs + bias
#pragma unroll
  for (int u = 0; u < 4; ++u) {
    const float bias = bo[o0 + u];
#pragma unroll
    for (int i = 0; i < 2; ++i) {
      float* dst = out + ((size_t)(n * kOUTC + o0 + u) * kH2 + (2 * h + i)) * kW2 + 2 * w;
      *(float2*)dst = make_float2(acc[u][i * 2] + bias, acc[u][i * 2 + 1] + bias);
    }
  }
}

extern "C" void kernel_launch(void* const* d_in, const int* in_sizes, int n_in,
                              void* d_out, int out_size, void* d_ws, size_t ws_size,
                              hipStream_t stream) {
  const float* x  = (const float*)d_in[0];   // (4,256,64,64)
  const float* wd = (const float*)d_in[1];   // (64,256,1,1)
  const float* bd = (const float*)d_in[2];   // (64,)
  const float* we = (const float*)d_in[3];   // (100,64,3,3)
  const float* be = (const float*)d_in[4];   // (100,)
  const float* wo = (const float*)d_in[5];   // (256,256,1,1)
  const float* bo = (const float*)d_in[6];   // (256,)
  float* out = (float*)d_out;                // (4,256,128,128)

  // workspace layout (floats): down | enc (softmaxed in place) | z
  float* down = (float*)d_ws;                // 4*64*4096  = 1,048,576
  float* enc  = down + 1048576;              // 4*100*4096 = 1,638,400
  float* z    = enc + 1638400;               // 4*256*4096 = 4,194,304

  k_down<<<1024, 256, 0, stream>>>(x, wd, bd, down);
  k_enc<<<1600, 256, 0, stream>>>(down, we, be, enc);
  k_softmax<<<256, 256, 0, stream>>>(enc);
  k_zgemm<<<1024, 256, 0, stream>>>(x, wo, z);
  k_fused_out<<<4096, 256, 0, stream>>>(z, enc, bo, out);
}